// Round 1
// baseline (201.782 us; speedup 1.0000x reference)
//
#include <hip/hip_runtime.h>
#include <math.h>

// ---- problem constants (fixed by reference) ----
#define T_TOK 1024
#define H_DIM 768
#define I_DIM 3072
#define E_NUM 8
#define BM    128
#define BK    64
#define MSLOTS 16   // max m-tiles: sum ceil(c_e/128) <= 8 + 7 = 15

typedef __attribute__((ext_vector_type(8))) short  short8;   // 8 bf16 (4 VGPRs)
typedef __attribute__((ext_vector_type(4))) float  f32x4;
typedef __attribute__((ext_vector_type(4))) int    int4v;

__device__ __forceinline__ unsigned short f2bf(float f) {
  union { float f; unsigned u; } a; a.f = f;
  unsigned r = a.u + 0x7FFFu + ((a.u >> 16) & 1u);  // RTNE
  return (unsigned short)(r >> 16);
}
__device__ __forceinline__ float gelu_exact(float x) {
  return 0.5f * x * (1.0f + erff(x * 0.70710678118654752f));
}
// XOR swizzle: row-major [row][BK] bf16 tile, spreads 8 consecutive rows
// across 8 distinct 16B slots -> conflict-free ds_read_b128 frag loads (G4).
__device__ __forceinline__ int swz(int row, int k) {
  return row * BK + (k ^ ((row & 7) << 3));
}

// ---- kernel 1: deterministic expert routing + tile list ----
__global__ void route_kernel(const int* __restrict__ eidx,
                             int* __restrict__ perm,
                             int* __restrict__ tile_e, int* __restrict__ tile_row,
                             int* __restrict__ tile_len, int* __restrict__ ntiles) {
  __shared__ int esh[T_TOK];
  __shared__ int offsh[E_NUM + 1];
  const int t = threadIdx.x;
  esh[t] = eidx[t];
  __syncthreads();
  const int e = esh[t];
  int pos = 0;
  for (int u = 0; u < T_TOK; ++u) {           // LDS broadcast reads: cheap
    const int eu = esh[u];
    pos += (eu < e) || (eu == e && u < t);    // stable rank -> deterministic
  }
  perm[pos] = t;
  if (t <= E_NUM) {
    int off = 0;
    for (int u = 0; u < T_TOK; ++u) off += (esh[u] < t);
    offsh[t] = off;
  }
  __syncthreads();
  if (t == 0) {
    int n = 0;
    for (int ee = 0; ee < E_NUM; ++ee)
      for (int r = offsh[ee]; r < offsh[ee + 1]; r += BM) {
        tile_e[n] = ee; tile_row[n] = r;
        tile_len[n] = min(offsh[ee + 1] - r, BM); ++n;
      }
    *ntiles = n;
    for (int i = n; i < MSLOTS; ++i) { tile_e[i] = 0; tile_row[i] = 0; tile_len[i] = 0; }
  }
}

// ---- kernel 2: gather x into perm order, f32 -> bf16 ----
__global__ void gather_kernel(const float* __restrict__ x,
                              const int* __restrict__ perm,
                              unsigned short* __restrict__ xg) {
  const int idx = blockIdx.x * 256 + threadIdx.x;
  if (idx >= T_TOK * (H_DIM / 8)) return;
  const int p = idx / (H_DIM / 8);
  const int c = (idx % (H_DIM / 8)) * 8;
  const int t = perm[p];
  const float* src = x + (size_t)t * H_DIM + c;
  const float4 v0 = *(const float4*)(src);
  const float4 v1 = *(const float4*)(src + 4);
  short8 o;
  o[0] = (short)f2bf(v0.x); o[1] = (short)f2bf(v0.y);
  o[2] = (short)f2bf(v0.z); o[3] = (short)f2bf(v0.w);
  o[4] = (short)f2bf(v1.x); o[5] = (short)f2bf(v1.y);
  o[6] = (short)f2bf(v1.z); o[7] = (short)f2bf(v1.w);
  *(short8*)(xg + (size_t)p * H_DIM + c) = o;
}

// ---- grouped GEMM: C[BM x BN] = A[perm rows] * W[e], fused epilogue ----
// IS_FFN1: +b1, exact gelu, store bf16 inter.  else: +b2, +residual, scatter f32 y.
template <int N_DIM, int K_DIM, int BN, bool IS_FFN1>
__global__ __launch_bounds__(256) void moe_gemm(
    const unsigned short* __restrict__ A,   // [T_TOK][K_DIM] bf16 (perm order)
    const float* __restrict__ W,            // [E][K_DIM][N_DIM] f32
    const float* __restrict__ bias,         // [E][N_DIM]
    const int* __restrict__ tile_e, const int* __restrict__ tile_row,
    const int* __restrict__ tile_len, const int* __restrict__ ntiles,
    unsigned short* __restrict__ out_bf,    // FFN1 out
    float* __restrict__ yout,               // FFN2 out
    const int* __restrict__ perm,
    const float* __restrict__ xres) {
  const int slot = blockIdx.y;
  if (slot >= *ntiles) return;
  const int e    = tile_e[slot];
  const int row0 = tile_row[slot];
  const int len  = tile_len[slot];
  const int n0   = blockIdx.x * BN;
  const float* We = W + (size_t)e * K_DIM * N_DIM;

  __shared__ unsigned short As[BM * BK];   // [row][k] swizzled
  __shared__ unsigned short Bs[BN * BK];   // [n][k]   swizzled (write-side transpose)

  const int tid  = threadIdx.x;
  const int lane = tid & 63;
  const int wave = tid >> 6;
  const int wr = wave >> 1, wc = wave & 1;     // 2x2 waves, each 64 x (BN/2)
  const int lr = lane & 15;
  const int lk = (lane >> 4) * 8;
  constexpr int NF  = BN / 32;                 // 16-wide n-frags per wave
  constexpr int BCH = BN / 16;                 // float4 chunks/thread for B stage

  f32x4 acc[4][NF] = {};

  for (int kt = 0; kt < K_DIM / BK; ++kt) {
    const int k0 = kt * BK;
    // global -> regs (A: bf16 16B chunks; rows past segment clamped, masked at store)
    int4v areg[4];
#pragma unroll
    for (int i = 0; i < 4; ++i) {
      const int c = tid + i * 256;
      const int r = c >> 3, kc = (c & 7) << 3;
      int grow = row0 + r; grow = grow < T_TOK ? grow : (T_TOK - 1);
      areg[i] = *(const int4v*)(A + (size_t)grow * K_DIM + (k0 + kc));
    }
    float4 breg[BCH];
#pragma unroll
    for (int i = 0; i < BCH; ++i) {
      const int c = tid + i * 256;
      const int k = c / (BN / 4), n4 = (c % (BN / 4)) * 4;
      breg[i] = *(const float4*)(We + (size_t)(k0 + k) * N_DIM + (n0 + n4));
    }
    __syncthreads();   // prior compute done before LDS overwrite
#pragma unroll
    for (int i = 0; i < 4; ++i) {
      const int c = tid + i * 256;
      const int r = c >> 3, kc = (c & 7) << 3;
      *(int4v*)(&As[swz(r, kc)]) = areg[i];
    }
#pragma unroll
    for (int i = 0; i < BCH; ++i) {
      const int c = tid + i * 256;
      const int k = c / (BN / 4), n4 = (c % (BN / 4)) * 4;
      Bs[swz(n4 + 0, k)] = f2bf(breg[i].x);
      Bs[swz(n4 + 1, k)] = f2bf(breg[i].y);
      Bs[swz(n4 + 2, k)] = f2bf(breg[i].z);
      Bs[swz(n4 + 3, k)] = f2bf(breg[i].w);
    }
    __syncthreads();
#pragma unroll
    for (int ks = 0; ks < 2; ++ks) {
      const int kk = ks * 32 + lk;
      short8 af[4], bfr[NF];
#pragma unroll
      for (int m = 0; m < 4; ++m)
        af[m] = *(const short8*)(&As[swz(wr * 64 + m * 16 + lr, kk)]);
#pragma unroll
      for (int n = 0; n < NF; ++n)
        bfr[n] = *(const short8*)(&Bs[swz(wc * (BN / 2) + n * 16 + lr, kk)]);
#pragma unroll
      for (int m = 0; m < 4; ++m)
#pragma unroll
        for (int n = 0; n < NF; ++n)
          acc[m][n] = __builtin_amdgcn_mfma_f32_16x16x32_bf16(af[m], bfr[n], acc[m][n], 0, 0, 0);
    }
  }

  // epilogue: C/D layout col=lane&15, row=(lane>>4)*4+j  [verified m89]
  const float* be = bias + (size_t)e * N_DIM;
#pragma unroll
  for (int n = 0; n < NF; ++n) {
    const int gc = n0 + wc * (BN / 2) + n * 16 + lr;
    const float bv = be[gc];
#pragma unroll
    for (int m = 0; m < 4; ++m) {
      const int rbase = wr * 64 + m * 16 + (lane >> 4) * 4;
#pragma unroll
      for (int j = 0; j < 4; ++j) {
        const int rl = rbase + j;
        if (rl < len) {
          const float v = acc[m][n][j] + bv;
          if constexpr (IS_FFN1) {
            out_bf[(size_t)(row0 + rl) * N_DIM + gc] = f2bf(gelu_exact(v));
          } else {
            const int t = perm[row0 + rl];
            yout[(size_t)t * N_DIM + gc] = v + xres[(size_t)t * N_DIM + gc];
          }
        }
      }
    }
  }
}

// ---- kernel 5: per-token LayerNorm ----
__global__ void ln_kernel(const float* __restrict__ y,
                          const float* __restrict__ gamma,
                          const float* __restrict__ beta,
                          float* __restrict__ out) {
  const int t = blockIdx.x;
  const int tid = threadIdx.x;  // 256
  const float* yr = y + (size_t)t * H_DIM;
  float v[3], s = 0.f, ss = 0.f;
#pragma unroll
  for (int i = 0; i < 3; ++i) { v[i] = yr[tid + i * 256]; s += v[i]; ss += v[i] * v[i]; }
#pragma unroll
  for (int o = 32; o; o >>= 1) { s += __shfl_down(s, o); ss += __shfl_down(ss, o); }
  __shared__ float ps[4], pss[4];
  __shared__ float mu_s, ir_s;
  const int w = tid >> 6;
  if ((tid & 63) == 0) { ps[w] = s; pss[w] = ss; }
  __syncthreads();
  if (tid == 0) {
    const float S = ps[0] + ps[1] + ps[2] + ps[3];
    const float SS = pss[0] + pss[1] + pss[2] + pss[3];
    const float mu = S * (1.0f / H_DIM);
    const float var = SS * (1.0f / H_DIM) - mu * mu;
    mu_s = mu; ir_s = rsqrtf(var + 1e-12f);
  }
  __syncthreads();
  const float mu = mu_s, ir = ir_s;
#pragma unroll
  for (int i = 0; i < 3; ++i) {
    const int c = tid + i * 256;
    out[(size_t)t * H_DIM + c] = (v[i] - mu) * ir * gamma[c] + beta[c];
  }
}

extern "C" void kernel_launch(void* const* d_in, const int* in_sizes, int n_in,
                              void* d_out, int out_size, void* d_ws, size_t ws_size,
                              hipStream_t stream) {
  const float* x     = (const float*)d_in[0];
  const int*   eidx  = (const int*)d_in[1];
  const float* W1    = (const float*)d_in[2];
  const float* b1    = (const float*)d_in[3];
  const float* W2    = (const float*)d_in[4];
  const float* b2    = (const float*)d_in[5];
  const float* gamma = (const float*)d_in[6];
  const float* beta  = (const float*)d_in[7];
  float* out = (float*)d_out;

  char* ws = (char*)d_ws;
  int* perm     = (int*)(ws);            // 4 KB
  int* tile_e   = (int*)(ws + 4096);
  int* tile_row = (int*)(ws + 4352);
  int* tile_len = (int*)(ws + 4608);
  int* ntiles   = (int*)(ws + 4864);
  unsigned short* xg    = (unsigned short*)(ws + 8192);            // 1.5 MB bf16
  unsigned short* inter = xg + (size_t)T_TOK * H_DIM;              // 6 MB bf16
  float* yb = (float*)(ws + 8192 + 2 * (size_t)T_TOK * (H_DIM + I_DIM));  // 3 MB f32
  // total ws use ~10.5 MB

  route_kernel<<<1, T_TOK, 0, stream>>>(eidx, perm, tile_e, tile_row, tile_len, ntiles);
  gather_kernel<<<(T_TOK * (H_DIM / 8) + 255) / 256, 256, 0, stream>>>(x, perm, xg);
  moe_gemm<I_DIM, H_DIM, 128, true><<<dim3(I_DIM / 128, MSLOTS), 256, 0, stream>>>(
      xg, W1, b1, tile_e, tile_row, tile_len, ntiles, inter, nullptr, nullptr, nullptr);
  moe_gemm<H_DIM, I_DIM, 64, false><<<dim3(H_DIM / 64, MSLOTS), 256, 0, stream>>>(
      inter, W2, b2, tile_e, tile_row, tile_len, ntiles, nullptr, yb, perm, x);
  ln_kernel<<<T_TOK, 256, 0, stream>>>(yb, gamma, beta, out);
  (void)in_sizes; (void)n_in; (void)out_size; (void)ws_size;
}

// Round 2
// 124.872 us; speedup vs baseline: 1.6159x; 1.6159x over previous
//
#include <hip/hip_runtime.h>
#include <math.h>

// ---- problem constants (fixed by reference) ----
#define T_TOK 1024
#define H_DIM 768
#define I_DIM 3072
#define E_NUM 8
#define BM    128
#define BK    64
#define MSLOTS 16   // max m-tiles: sum ceil(c_e/128) <= 8 + 7 = 15
#define KSPLIT2 4   // FFN2 split-K factor

typedef __attribute__((ext_vector_type(8))) short  short8;   // 8 bf16 (4 VGPRs)
typedef __attribute__((ext_vector_type(4))) float  f32x4;
typedef __attribute__((ext_vector_type(4))) int    int4v;

__device__ __forceinline__ unsigned short f2bf(float f) {
  union { float f; unsigned u; } a; a.f = f;
  unsigned r = a.u + 0x7FFFu + ((a.u >> 16) & 1u);  // RTNE
  return (unsigned short)(r >> 16);
}
__device__ __forceinline__ float gelu_exact(float x) {
  return 0.5f * x * (1.0f + erff(x * 0.70710678118654752f));
}
// XOR swizzle: row-major [row][BK] bf16 tile -> conflict-free ds_read_b128 (G4).
__device__ __forceinline__ int swz(int row, int k) {
  return row * BK + (k ^ ((row & 7) << 3));
}

// ---- kernel 1: deterministic expert routing + tile list ----
__global__ void route_kernel(const int* __restrict__ eidx,
                             int* __restrict__ perm,
                             int* __restrict__ tile_e, int* __restrict__ tile_row,
                             int* __restrict__ tile_len, int* __restrict__ ntiles) {
  __shared__ int esh[T_TOK];
  __shared__ int offsh[E_NUM + 1];
  const int t = threadIdx.x;
  esh[t] = eidx[t];
  __syncthreads();
  const int e = esh[t];
  int pos = 0;
  for (int u = 0; u < T_TOK; ++u) {
    const int eu = esh[u];
    pos += (eu < e) || (eu == e && u < t);    // stable rank -> deterministic
  }
  perm[pos] = t;
  if (t <= E_NUM) {
    int off = 0;
    for (int u = 0; u < T_TOK; ++u) off += (esh[u] < t);
    offsh[t] = off;
  }
  __syncthreads();
  if (t == 0) {
    int n = 0;
    for (int ee = 0; ee < E_NUM; ++ee)
      for (int r = offsh[ee]; r < offsh[ee + 1]; r += BM) {
        tile_e[n] = ee; tile_row[n] = r;
        tile_len[n] = min(offsh[ee + 1] - r, BM); ++n;
      }
    *ntiles = n;
    for (int i = n; i < MSLOTS; ++i) { tile_e[i] = 0; tile_row[i] = 0; tile_len[i] = 0; }
  }
}

// ---- kernel 2: gather x into perm order, f32 -> bf16 ----
__global__ void gather_kernel(const float* __restrict__ x,
                              const int* __restrict__ perm,
                              unsigned short* __restrict__ xg) {
  const int idx = blockIdx.x * 256 + threadIdx.x;
  if (idx >= T_TOK * (H_DIM / 8)) return;
  const int p = idx / (H_DIM / 8);
  const int c = (idx % (H_DIM / 8)) * 8;
  const int t = perm[p];
  const float* src = x + (size_t)t * H_DIM + c;
  const float4 v0 = *(const float4*)(src);
  const float4 v1 = *(const float4*)(src + 4);
  short8 o;
  o[0] = (short)f2bf(v0.x); o[1] = (short)f2bf(v0.y);
  o[2] = (short)f2bf(v0.z); o[3] = (short)f2bf(v0.w);
  o[4] = (short)f2bf(v1.x); o[5] = (short)f2bf(v1.y);
  o[6] = (short)f2bf(v1.z); o[7] = (short)f2bf(v1.w);
  *(short8*)(xg + (size_t)p * H_DIM + c) = o;
}

// ---- grouped GEMM, BM=128 x BN=64, pipelined (dbuf LDS, 1 raw barrier/iter) ----
// IS_FFN1: +b1, exact gelu, store bf16 inter (perm order).
// else:    store raw f32 partial to part[blockIdx.z] (bias/residual/sum in LN).
template <int N_FULL, int K_FULL, int KLOOP, bool IS_FFN1>
__global__ __launch_bounds__(256) void moe_gemm(
    const unsigned short* __restrict__ A,   // [T_TOK][K_FULL] bf16 (perm order)
    const float* __restrict__ W,            // [E][K_FULL][N_FULL] f32
    const float* __restrict__ bias,         // [E][N_FULL] (FFN1 only)
    const int* __restrict__ tile_e, const int* __restrict__ tile_row,
    const int* __restrict__ tile_len, const int* __restrict__ ntiles,
    unsigned short* __restrict__ out_bf,    // FFN1 out
    float* __restrict__ part) {             // FFN2 partials [KSPLIT2][T_TOK][N_FULL]
  constexpr int BN  = 64;
  constexpr int NF  = BN / 32;      // 2 n-frags per wave
  constexpr int BCH = BN / 16;      // 4 float4 chunks/thread for B stage
  constexpr int KT  = KLOOP / BK;   // 12

  const int slot = blockIdx.y;
  if (slot >= *ntiles) return;
  const int e    = tile_e[slot];
  const int row0 = tile_row[slot];
  const int len  = tile_len[slot];
  const int n0   = blockIdx.x * BN;
  const int kbase = blockIdx.z * KLOOP;
  const float* We = W + (size_t)e * K_FULL * N_FULL;

  __shared__ unsigned short As[2][BM * BK];   // 2 x 16 KB
  __shared__ unsigned short Bs[2][BN * BK];   // 2 x  8 KB

  const int tid  = threadIdx.x;
  const int lane = tid & 63;
  const int wave = tid >> 6;
  const int wr = wave >> 1, wc = wave & 1;     // 2x2 waves: 64 rows x 32 cols each
  const int lr = lane & 15;
  const int lk = (lane >> 4) * 8;

  f32x4 acc[4][NF] = {};
  int4v areg[4];
  float4 breg[BCH];

  auto load_tile = [&](int kt) {
    const int k0 = kbase + kt * BK;
#pragma unroll
    for (int i = 0; i < 4; ++i) {
      const int c = tid + i * 256;
      const int r = c >> 3, kc = (c & 7) << 3;
      int grow = row0 + r; grow = grow < T_TOK ? grow : (T_TOK - 1);
      areg[i] = *(const int4v*)(A + (size_t)grow * K_FULL + k0 + kc);
    }
#pragma unroll
    for (int i = 0; i < BCH; ++i) {
      const int c = tid + i * 256;
      const int k = c / (BN / 4), n4 = (c % (BN / 4)) * 4;
      breg[i] = *(const float4*)(We + (size_t)(k0 + k) * N_FULL + (n0 + n4));
    }
  };

  load_tile(0);
  for (int kt = 0; kt < KT; ++kt) {
    const int cur = kt & 1;
    // regs -> LDS[cur] (compiler waits vmcnt only for this tile's loads)
#pragma unroll
    for (int i = 0; i < 4; ++i) {
      const int c = tid + i * 256;
      const int r = c >> 3, kc = (c & 7) << 3;
      *(int4v*)(&As[cur][swz(r, kc)]) = areg[i];
    }
#pragma unroll
    for (int i = 0; i < BCH; ++i) {
      const int c = tid + i * 256;
      const int k = c / (BN / 4), n4 = (c % (BN / 4)) * 4;
      Bs[cur][swz(n4 + 0, k)] = f2bf(breg[i].x);
      Bs[cur][swz(n4 + 1, k)] = f2bf(breg[i].y);
      Bs[cur][swz(n4 + 2, k)] = f2bf(breg[i].z);
      Bs[cur][swz(n4 + 3, k)] = f2bf(breg[i].w);
    }
    // prefetch next tile: loads stay in flight across the barrier (no vmcnt drain)
    if (kt + 1 < KT) load_tile(kt + 1);
    asm volatile("s_waitcnt lgkmcnt(0)" ::: "memory");  // my ds_writes done
    __builtin_amdgcn_s_barrier();                       // all waves' writes done
    __builtin_amdgcn_sched_barrier(0);
#pragma unroll
    for (int ks = 0; ks < 2; ++ks) {
      const int kk = ks * 32 + lk;
      short8 af[4], bfr[NF];
#pragma unroll
      for (int m = 0; m < 4; ++m)
        af[m] = *(const short8*)(&As[cur][swz(wr * 64 + m * 16 + lr, kk)]);
#pragma unroll
      for (int n = 0; n < NF; ++n)
        bfr[n] = *(const short8*)(&Bs[cur][swz(wc * 32 + n * 16 + lr, kk)]);
#pragma unroll
      for (int m = 0; m < 4; ++m)
#pragma unroll
        for (int n = 0; n < NF; ++n)
          acc[m][n] = __builtin_amdgcn_mfma_f32_16x16x32_bf16(af[m], bfr[n], acc[m][n], 0, 0, 0);
    }
  }

  // epilogue: C/D layout col=lane&15, row=(lane>>4)*4+j  [verified m89]
#pragma unroll
  for (int n = 0; n < NF; ++n) {
    const int gc = n0 + wc * 32 + n * 16 + lr;
    float bv = 0.f;
    if constexpr (IS_FFN1) bv = bias[(size_t)e * N_FULL + gc];
#pragma unroll
    for (int m = 0; m < 4; ++m) {
      const int rbase = wr * 64 + m * 16 + (lane >> 4) * 4;
#pragma unroll
      for (int j = 0; j < 4; ++j) {
        const int rl = rbase + j;
        if (rl < len) {
          if constexpr (IS_FFN1) {
            out_bf[(size_t)(row0 + rl) * N_FULL + gc] = f2bf(gelu_exact(acc[m][n][j] + bv));
          } else {
            part[((size_t)blockIdx.z * T_TOK + row0 + rl) * N_FULL + gc] = acc[m][n][j];
          }
        }
      }
    }
  }
}

// ---- kernel 5: split-K sum + bias2 + residual + LayerNorm (one block per perm idx) ----
__global__ void ln_kernel(const float* __restrict__ part,
                          const float* __restrict__ x,
                          const int* __restrict__ perm,
                          const int* __restrict__ eidx,
                          const float* __restrict__ b2,
                          const float* __restrict__ gamma,
                          const float* __restrict__ beta,
                          float* __restrict__ out) {
  const int p = blockIdx.x;
  const int tid = threadIdx.x;  // 256
  const int t = perm[p];
  const int e = eidx[t];
  float v[3], s = 0.f, ss = 0.f;
#pragma unroll
  for (int i = 0; i < 3; ++i) {
    const int c = tid + i * 256;
    float a = x[(size_t)t * H_DIM + c] + b2[(size_t)e * H_DIM + c];
#pragma unroll
    for (int s4 = 0; s4 < KSPLIT2; ++s4)
      a += part[((size_t)s4 * T_TOK + p) * H_DIM + c];
    v[i] = a; s += a; ss += a * a;
  }
#pragma unroll
  for (int o = 32; o; o >>= 1) { s += __shfl_down(s, o); ss += __shfl_down(ss, o); }
  __shared__ float ps[4], pss[4];
  __shared__ float mu_s, ir_s;
  const int w = tid >> 6;
  if ((tid & 63) == 0) { ps[w] = s; pss[w] = ss; }
  __syncthreads();
  if (tid == 0) {
    const float S = ps[0] + ps[1] + ps[2] + ps[3];
    const float SS = pss[0] + pss[1] + pss[2] + pss[3];
    const float mu = S * (1.0f / H_DIM);
    const float var = SS * (1.0f / H_DIM) - mu * mu;
    mu_s = mu; ir_s = rsqrtf(var + 1e-12f);
  }
  __syncthreads();
  const float mu = mu_s, ir = ir_s;
#pragma unroll
  for (int i = 0; i < 3; ++i) {
    const int c = tid + i * 256;
    out[(size_t)t * H_DIM + c] = (v[i] - mu) * ir * gamma[c] + beta[c];
  }
}

extern "C" void kernel_launch(void* const* d_in, const int* in_sizes, int n_in,
                              void* d_out, int out_size, void* d_ws, size_t ws_size,
                              hipStream_t stream) {
  const float* x     = (const float*)d_in[0];
  const int*   eidx  = (const int*)d_in[1];
  const float* W1    = (const float*)d_in[2];
  const float* b1    = (const float*)d_in[3];
  const float* W2    = (const float*)d_in[4];
  const float* b2    = (const float*)d_in[5];
  const float* gamma = (const float*)d_in[6];
  const float* beta  = (const float*)d_in[7];
  float* out = (float*)d_out;

  char* ws = (char*)d_ws;
  int* perm     = (int*)(ws);
  int* tile_e   = (int*)(ws + 4096);
  int* tile_row = (int*)(ws + 4352);
  int* tile_len = (int*)(ws + 4608);
  int* ntiles   = (int*)(ws + 4864);
  unsigned short* xg    = (unsigned short*)(ws + 8192);          // 1.5 MB bf16
  unsigned short* inter = xg + (size_t)T_TOK * H_DIM;            // 6 MB bf16
  float* part = (float*)(ws + 8192 + 2 * (size_t)T_TOK * (H_DIM + I_DIM)); // 12 MB f32
  // total ws use ~20.5 MB

  route_kernel<<<1, T_TOK, 0, stream>>>(eidx, perm, tile_e, tile_row, tile_len, ntiles);
  gather_kernel<<<(T_TOK * (H_DIM / 8) + 255) / 256, 256, 0, stream>>>(x, perm, xg);
  // FFN1: N=3072, K=768, no split-K. grid 48 x 16 = 768 blocks
  moe_gemm<I_DIM, H_DIM, H_DIM, true><<<dim3(I_DIM / 64, MSLOTS, 1), 256, 0, stream>>>(
      xg, W1, b1, tile_e, tile_row, tile_len, ntiles, inter, nullptr);
  // FFN2: N=768, K=3072 split 4 x 768. grid 12 x 16 x 4 = 768 blocks
  moe_gemm<H_DIM, I_DIM, I_DIM / KSPLIT2, false><<<dim3(H_DIM / 64, MSLOTS, KSPLIT2), 256, 0, stream>>>(
      inter, W2, nullptr, tile_e, tile_row, tile_len, ntiles, nullptr, part);
  ln_kernel<<<T_TOK, 256, 0, stream>>>(part, x, perm, eidx, b2, gamma, beta, out);
  (void)in_sizes; (void)n_in; (void)out_size; (void)ws_size;
}

// Round 3
// 77.109 us; speedup vs baseline: 2.6168x; 1.6194x over previous
//
#include <hip/hip_runtime.h>
#include <math.h>

// ---- problem constants (fixed by reference) ----
#define T_TOK 1024
#define H_DIM 768
#define I_DIM 3072
#define E_NUM 8
#define BM    128
#define BK    64
#define MSLOTS 16   // max m-tiles: sum ceil(c_e/128) <= 8 + 7 = 15
#define KSPLIT2 4   // FFN2 split-K factor

typedef __attribute__((ext_vector_type(8))) short  short8;   // 8 bf16 (4 VGPRs)
typedef __attribute__((ext_vector_type(4))) float  f32x4;
typedef __attribute__((ext_vector_type(4))) int    int4v;

__device__ __forceinline__ unsigned short f2bf(float f) {
  union { float f; unsigned u; } a; a.f = f;
  unsigned r = a.u + 0x7FFFu + ((a.u >> 16) & 1u);  // RTNE
  return (unsigned short)(r >> 16);
}
__device__ __forceinline__ float gelu_exact(float x) {
  return 0.5f * x * (1.0f + erff(x * 0.70710678118654752f));
}
// XOR swizzle: row-major [row][BK] bf16 tile -> conflict-free ds_read_b128 (G4).
__device__ __forceinline__ int swz(int row, int k) {
  return row * BK + (k ^ ((row & 7) << 3));
}

// ---- kernel 1: deterministic expert routing (ballot rank) + tile list ----
__global__ __launch_bounds__(1024) void route_kernel(
    const int* __restrict__ eidx, int* __restrict__ perm,
    int* __restrict__ tile_e, int* __restrict__ tile_row,
    int* __restrict__ tile_len, int* __restrict__ ntiles) {
  __shared__ int wcnt[16][E_NUM];   // per-wave per-expert count
  __shared__ int wpre[16][E_NUM];   // exclusive prefix over waves
  __shared__ int offsh[E_NUM + 1];
  const int t = threadIdx.x;        // 1024
  const int lane = t & 63, wave = t >> 6;
  const int e = eidx[t];
  unsigned long long myMask = 0;
#pragma unroll
  for (int ee = 0; ee < E_NUM; ++ee) {
    unsigned long long m = __ballot(e == ee);
    if (ee == e) myMask = m;
    if (lane == 0) wcnt[wave][ee] = __popcll(m);
  }
  const int rank = __popcll(myMask & ((1ull << lane) - 1ull));
  __syncthreads();
  if (t < 16 * E_NUM) {             // pair (w, e)
    const int w = t >> 3, ee = t & 7;
    int p = 0;
    for (int w2 = 0; w2 < w; ++w2) p += wcnt[w2][ee];
    wpre[w][ee] = p;
  }
  __syncthreads();
  if (t <= E_NUM) {
    int off = 0;
    for (int ee = 0; ee < t; ++ee) off += wpre[15][ee] + wcnt[15][ee];
    offsh[t] = off;
  }
  __syncthreads();
  perm[offsh[e] + wpre[wave][e] + rank] = t;
  if (t == 0) {
    int n = 0;
    for (int ee = 0; ee < E_NUM; ++ee)
      for (int r = offsh[ee]; r < offsh[ee + 1]; r += BM) {
        tile_e[n] = ee; tile_row[n] = r;
        tile_len[n] = min(offsh[ee + 1] - r, BM); ++n;
      }
    *ntiles = n;
    for (int i = n; i < MSLOTS; ++i) { tile_e[i] = 0; tile_row[i] = 0; tile_len[i] = 0; }
  }
}

// ---- kernel 2: gather x into perm order, f32 -> bf16 ----
__global__ void gather_kernel(const float* __restrict__ x,
                              const int* __restrict__ perm,
                              unsigned short* __restrict__ xg) {
  const int idx = blockIdx.x * 256 + threadIdx.x;
  if (idx >= T_TOK * (H_DIM / 8)) return;
  const int p = idx / (H_DIM / 8);
  const int c = (idx % (H_DIM / 8)) * 8;
  const int t = perm[p];
  const float* src = x + (size_t)t * H_DIM + c;
  const float4 v0 = *(const float4*)(src);
  const float4 v1 = *(const float4*)(src + 4);
  short8 o;
  o[0] = (short)f2bf(v0.x); o[1] = (short)f2bf(v0.y);
  o[2] = (short)f2bf(v0.z); o[3] = (short)f2bf(v0.w);
  o[4] = (short)f2bf(v1.x); o[5] = (short)f2bf(v1.y);
  o[6] = (short)f2bf(v1.z); o[7] = (short)f2bf(v1.w);
  *(short8*)(xg + (size_t)p * H_DIM + c) = o;
}

// ---- grouped GEMM, BM=128 x BN=64, 2-deep prefetch, dbuf LDS, 1 barrier/iter --
template <int N_FULL, int K_FULL, int KLOOP, bool IS_FFN1>
__global__ __launch_bounds__(256, 3) void moe_gemm(
    const unsigned short* __restrict__ A,   // [T_TOK][K_FULL] bf16 (perm order)
    const float* __restrict__ W,            // [E][K_FULL][N_FULL] f32
    const float* __restrict__ bias,         // [E][N_FULL] (FFN1 only)
    const int* __restrict__ tile_e, const int* __restrict__ tile_row,
    const int* __restrict__ tile_len, const int* __restrict__ ntiles,
    unsigned short* __restrict__ out_bf,    // FFN1 out
    float* __restrict__ part) {             // FFN2 partials [KSPLIT2][T_TOK][N_FULL]
  constexpr int BN = 64;
  constexpr int NF = BN / 32;       // 2 n-frags per wave
  constexpr int KT = KLOOP / BK;    // 12 (even)

  const int slot = blockIdx.y;
  if (slot >= *ntiles) return;
  const int e    = tile_e[slot];
  const int row0 = tile_row[slot];
  const int len  = tile_len[slot];
  const int n0   = blockIdx.x * BN;
  const int kbase = blockIdx.z * KLOOP;
  const float* We = W + (size_t)e * K_FULL * N_FULL;

  __shared__ unsigned short As[2][BM * BK];   // 2 x 16 KB
  __shared__ unsigned short Bs[2][BN * BK];   // 2 x  8 KB

  const int tid  = threadIdx.x;
  const int lane = tid & 63;
  const int wave = tid >> 6;
  const int wr = wave >> 1, wc = wave & 1;     // 2x2 waves: 64 rows x 32 cols each
  const int lr = lane & 15;
  const int lk = (lane >> 4) * 8;
  const int bn = tid & 63;                     // B stage: my column
  const int kb = tid >> 6;                     // B stage: my 16-k block

  f32x4 acc[4][NF] = {};
  int4v areg0[4], areg1[4];
  float breg0[16], breg1[16];

  auto load_tile = [&](int kt, int4v* ar, float* br) {
    const int k0 = kbase + kt * BK;
#pragma unroll
    for (int i = 0; i < 4; ++i) {
      const int c = tid + i * 256;
      const int r = c >> 3, kc = (c & 7) << 3;
      int grow = row0 + r; grow = grow < T_TOK ? grow : (T_TOK - 1);
      ar[i] = *(const int4v*)(A + (size_t)grow * K_FULL + k0 + kc);
    }
    const float* wp = We + (size_t)(k0 + kb * 16) * N_FULL + n0 + bn;
#pragma unroll
    for (int j = 0; j < 16; ++j)
      br[j] = wp[(size_t)j * N_FULL];          // coalesced across lanes (n)
  };
  auto store_lds = [&](int buf, const int4v* ar, const float* br) {
#pragma unroll
    for (int i = 0; i < 4; ++i) {
      const int c = tid + i * 256;
      const int r = c >> 3, kc = (c & 7) << 3;
      *(int4v*)(&As[buf][swz(r, kc)]) = ar[i];
    }
    short8 p0, p1;
#pragma unroll
    for (int j = 0; j < 8; ++j) { p0[j] = (short)f2bf(br[j]); p1[j] = (short)f2bf(br[8 + j]); }
    *(short8*)(&Bs[buf][swz(bn, kb * 16)])     = p0;
    *(short8*)(&Bs[buf][swz(bn, kb * 16 + 8)]) = p1;
  };
  auto mfma_tile = [&](int buf) {
#pragma unroll
    for (int ks = 0; ks < 2; ++ks) {
      const int kk = ks * 32 + lk;
      short8 af[4], bfr[NF];
#pragma unroll
      for (int m = 0; m < 4; ++m)
        af[m] = *(const short8*)(&As[buf][swz(wr * 64 + m * 16 + lr, kk)]);
#pragma unroll
      for (int n = 0; n < NF; ++n)
        bfr[n] = *(const short8*)(&Bs[buf][swz(wc * 32 + n * 16 + lr, kk)]);
#pragma unroll
      for (int m = 0; m < 4; ++m)
#pragma unroll
        for (int n = 0; n < NF; ++n)
          acc[m][n] = __builtin_amdgcn_mfma_f32_16x16x32_bf16(af[m], bfr[n], acc[m][n], 0, 0, 0);
    }
  };

  load_tile(0, areg0, breg0);
  load_tile(1, areg1, breg1);
#pragma unroll 1
  for (int kt = 0; kt < KT; kt += 2) {
    store_lds(0, areg0, breg0);
    if (kt + 2 < KT) load_tile(kt + 2, areg0, breg0);
    asm volatile("s_waitcnt lgkmcnt(0)" ::: "memory");
    __builtin_amdgcn_s_barrier();
    __builtin_amdgcn_sched_barrier(0);
    mfma_tile(0);
    store_lds(1, areg1, breg1);
    if (kt + 3 < KT) load_tile(kt + 3, areg1, breg1);
    asm volatile("s_waitcnt lgkmcnt(0)" ::: "memory");
    __builtin_amdgcn_s_barrier();
    __builtin_amdgcn_sched_barrier(0);
    mfma_tile(1);
  }

  // epilogue: C/D layout col=lane&15, row=(lane>>4)*4+j  [verified m89]
#pragma unroll
  for (int n = 0; n < NF; ++n) {
    const int gc = n0 + wc * 32 + n * 16 + lr;
    float bv = 0.f;
    if constexpr (IS_FFN1) bv = bias[(size_t)e * N_FULL + gc];
#pragma unroll
    for (int m = 0; m < 4; ++m) {
      const int rbase = wr * 64 + m * 16 + (lane >> 4) * 4;
#pragma unroll
      for (int j = 0; j < 4; ++j) {
        const int rl = rbase + j;
        if (rl < len) {
          if constexpr (IS_FFN1) {
            out_bf[(size_t)(row0 + rl) * N_FULL + gc] = f2bf(gelu_exact(acc[m][n][j] + bv));
          } else {
            part[((size_t)blockIdx.z * T_TOK + row0 + rl) * N_FULL + gc] = acc[m][n][j];
          }
        }
      }
    }
  }
}

// ---- kernel 5: split-K sum + bias2 + residual + LayerNorm ----
__global__ void ln_kernel(const float* __restrict__ part,
                          const float* __restrict__ x,
                          const int* __restrict__ perm,
                          const int* __restrict__ eidx,
                          const float* __restrict__ b2,
                          const float* __restrict__ gamma,
                          const float* __restrict__ beta,
                          float* __restrict__ out) {
  const int p = blockIdx.x;
  const int tid = threadIdx.x;  // 256
  const int t = perm[p];
  const int e = eidx[t];
  float v[3], s = 0.f, ss = 0.f;
#pragma unroll
  for (int i = 0; i < 3; ++i) {
    const int c = tid + i * 256;
    float a = x[(size_t)t * H_DIM + c] + b2[(size_t)e * H_DIM + c];
#pragma unroll
    for (int s4 = 0; s4 < KSPLIT2; ++s4)
      a += part[((size_t)s4 * T_TOK + p) * H_DIM + c];
    v[i] = a; s += a; ss += a * a;
  }
#pragma unroll
  for (int o = 32; o; o >>= 1) { s += __shfl_down(s, o); ss += __shfl_down(ss, o); }
  __shared__ float ps[4], pss[4];
  __shared__ float mu_s, ir_s;
  const int w = tid >> 6;
  if ((tid & 63) == 0) { ps[w] = s; pss[w] = ss; }
  __syncthreads();
  if (tid == 0) {
    const float S = ps[0] + ps[1] + ps[2] + ps[3];
    const float SS = pss[0] + pss[1] + pss[2] + pss[3];
    const float mu = S * (1.0f / H_DIM);
    const float var = SS * (1.0f / H_DIM) - mu * mu;
    mu_s = mu; ir_s = rsqrtf(var + 1e-12f);
  }
  __syncthreads();
  const float mu = mu_s, ir = ir_s;
#pragma unroll
  for (int i = 0; i < 3; ++i) {
    const int c = tid + i * 256;
    out[(size_t)t * H_DIM + c] = (v[i] - mu) * ir * gamma[c] + beta[c];
  }
}

extern "C" void kernel_launch(void* const* d_in, const int* in_sizes, int n_in,
                              void* d_out, int out_size, void* d_ws, size_t ws_size,
                              hipStream_t stream) {
  const float* x     = (const float*)d_in[0];
  const int*   eidx  = (const int*)d_in[1];
  const float* W1    = (const float*)d_in[2];
  const float* b1    = (const float*)d_in[3];
  const float* W2    = (const float*)d_in[4];
  const float* b2    = (const float*)d_in[5];
  const float* gamma = (const float*)d_in[6];
  const float* beta  = (const float*)d_in[7];
  float* out = (float*)d_out;

  char* ws = (char*)d_ws;
  int* perm     = (int*)(ws);
  int* tile_e   = (int*)(ws + 4096);
  int* tile_row = (int*)(ws + 4352);
  int* tile_len = (int*)(ws + 4608);
  int* ntiles   = (int*)(ws + 4864);
  unsigned short* xg    = (unsigned short*)(ws + 8192);          // 1.5 MB bf16
  unsigned short* inter = xg + (size_t)T_TOK * H_DIM;            // 6 MB bf16
  float* part = (float*)(ws + 8192 + 2 * (size_t)T_TOK * (H_DIM + I_DIM)); // 12 MB f32

  route_kernel<<<1, T_TOK, 0, stream>>>(eidx, perm, tile_e, tile_row, tile_len, ntiles);
  gather_kernel<<<(T_TOK * (H_DIM / 8) + 255) / 256, 256, 0, stream>>>(x, perm, xg);
  // FFN1: N=3072, K=768. grid 48 x 16 = 768 blocks
  moe_gemm<I_DIM, H_DIM, H_DIM, true><<<dim3(I_DIM / 64, MSLOTS, 1), 256, 0, stream>>>(
      xg, W1, b1, tile_e, tile_row, tile_len, ntiles, inter, nullptr);
  // FFN2: N=768, K=3072 split 4 x 768. grid 12 x 16 x 4 = 768 blocks
  moe_gemm<H_DIM, I_DIM, I_DIM / KSPLIT2, false><<<dim3(H_DIM / 64, MSLOTS, KSPLIT2), 256, 0, stream>>>(
      inter, W2, nullptr, tile_e, tile_row, tile_len, ntiles, nullptr, part);
  ln_kernel<<<T_TOK, 256, 0, stream>>>(part, x, perm, eidx, b2, gamma, beta, out);
  (void)in_sizes; (void)n_in; (void)out_size; (void)ws_size;
}